// Round 4
// baseline (20981.090 us; speedup 1.0000x reference)
//
#include <hip/hip_runtime.h>
#include <cstdint>

#define Bb 32
#define Cc 512
#define Nn 384
#define Vv 600
#define Ee 256
#define Dd 512
#define Tt 192
#define Ss 191
#define EOS_TOK 130
#define BD (Bb*Dd)          // 16384
#define NBLK 256
#define NTHR 512

// ---- ws layout (float offsets) ----
// Memory model (proven r0/r1): buffers are either (a) per-step-unique,
// written ONCE via sc1 write-through, then plain-loaded (first-plain-touch =>
// consumer L2 can hold no stale copy; per-XCD L2 dedups the broadcast), or
// (b) rewritten (qB/ctxB/den/flags) on the sc1/atomic path.
#define OFF_TOK   0                           // int tok[Ss*Bb]
#define OFF_SHIFT 8192                        // float shift[1]
#define OFF_WV    8256                        // Bb*Nn*Dd = 6291456
#define OFF_DEN   (OFF_WV + 6291456)          // denom[t][b] (pad 8192)
#define OFF_QB    (OFF_DEN + 8192)            // q[b][d] 32*512 (rewritten, sc1)
#define OFF_CTXB  (OFF_QB + 16384)            // ctx[par][b][c] 2*16384 (atomics+sc1)
#define OFF_EMBP  (OFF_CTXB + 32768)          // embP[t][k][32b] 191*8192 (write-once)
#define OFF_HXP   (OFF_EMBP + 191*8192)       // hxP[t][d][32b] 191*16384 (write-once)
#define OFF_HXBP  (OFF_HXP + 191*16384)       // hxBP[t][b][d] 191*16384 (write-once)
#define OFF_XOTP  (OFF_HXBP + 191*16384)      // xoTP[t][d][32b] 191*16384 (write-once)
#define OFF_OBUF  (OFF_XOTP + 191*16384)      // obuf[t+1][b][d] 192*16384 (write-once)
#define OFF_BAR   (OFF_OBUF + 192*16384)      // flags[256*16] + genv[32*16]

#define LOGITS_SZ (Bb*Ss*Vv)  // 3667200
#define ALPHA_SZ  (Bb*Ss*Nn)  // 2347008

__device__ __forceinline__ float sigm_(float x) {
    float e = __expf(-x);
    return __builtin_amdgcn_rcpf(1.0f + e);
}
__device__ __forceinline__ float tanh_(float x) {
    float xc = fminf(15.0f, fmaxf(-15.0f, x));
    float e = __expf(2.0f * xc);
    return (e - 1.0f) * __builtin_amdgcn_rcpf(e + 1.0f);
}

__device__ __forceinline__ void st_dev(float* p, float v) {
    __hip_atomic_store(p, v, __ATOMIC_RELAXED, __HIP_MEMORY_SCOPE_AGENT);
}
__device__ __forceinline__ float ld1_dev(const float* p) {
    return __hip_atomic_load(p, __ATOMIC_RELAXED, __HIP_MEMORY_SCOPE_AGENT);
}
__device__ __forceinline__ float2 ld2_dev(const float* p) {
    unsigned long long u = __hip_atomic_load((const unsigned long long*)p,
                                             __ATOMIC_RELAXED,
                                             __HIP_MEMORY_SCOPE_AGENT);
    float2 f;
    f.x = __uint_as_float((unsigned int)u);
    f.y = __uint_as_float((unsigned int)(u >> 32));
    return f;
}

// Flag-array device barrier (byte-identical protocol to round 3).
__device__ __forceinline__ void gbar(int* flags, int* genv, int ibar) {
    __syncthreads();   // drains vmcnt: all sc1 data stores ack'd
    const int target = ibar + 1;
    if (threadIdx.x == 0)
        __hip_atomic_store(&flags[blockIdx.x * 16], target, __ATOMIC_RELAXED,
                           __HIP_MEMORY_SCOPE_AGENT);
    if (blockIdx.x == 0) {
        if (threadIdx.x < 64) {
            int l = threadIdx.x * 4;
            for (;;) {
                int f0 = __hip_atomic_load(&flags[(l + 0) * 16], __ATOMIC_RELAXED,
                                           __HIP_MEMORY_SCOPE_AGENT);
                int f1 = __hip_atomic_load(&flags[(l + 1) * 16], __ATOMIC_RELAXED,
                                           __HIP_MEMORY_SCOPE_AGENT);
                int f2 = __hip_atomic_load(&flags[(l + 2) * 16], __ATOMIC_RELAXED,
                                           __HIP_MEMORY_SCOPE_AGENT);
                int f3 = __hip_atomic_load(&flags[(l + 3) * 16], __ATOMIC_RELAXED,
                                           __HIP_MEMORY_SCOPE_AGENT);
                if (__all(f0 >= target && f1 >= target &&
                          f2 >= target && f3 >= target)) break;
                __builtin_amdgcn_s_sleep(1);
            }
            if (threadIdx.x < 32)
                __hip_atomic_store(&genv[threadIdx.x * 16], target,
                                   __ATOMIC_RELAXED, __HIP_MEMORY_SCOPE_AGENT);
        }
    } else if (threadIdx.x == 0) {
        int* g = &genv[(blockIdx.x >> 3) * 16];
        while (__hip_atomic_load(g, __ATOMIC_RELAXED,
                                 __HIP_MEMORY_SCOPE_AGENT) < target)
            __builtin_amdgcn_s_sleep(2);
    }
    __syncthreads();
}

// S0: zero den/flags, token sequence, exp-shift = sum|v|.
__global__ void k_setup(const int* __restrict__ tgt, const float* __restrict__ vv,
                        float* denb, int* bar, int* tok, float* shiftbuf) {
    int gid = blockIdx.x * 256 + threadIdx.x;
    if (gid < 8192) denb[gid] = 0.f;
    if (gid < 4608) bar[gid] = 0;
    if (blockIdx.x == 0) {
        __shared__ int is64;
        if (threadIdx.x == 0) {
            int a = 1;
            for (int k = 0; k < 32; ++k) if (tgt[2 * k + 1] != 0) a = 0;
            is64 = a;
        }
        __syncthreads();
        int b = threadIdx.x;
        if (b < Bb) {
            int fin = 0;
            tok[0 * Bb + b] = 0;
            for (int s = 1; s < Ss; ++s) {
                int li = b * Tt + s;
                int nt = is64 ? tgt[2 * li] : tgt[li];
                if (nt == EOS_TOK) fin = 1;
                tok[s * Bb + b] = fin ? 0 : nt;
            }
        }
    }
    if (blockIdx.x == 1) {
        __shared__ float sred[256];
        int tid = threadIdx.x;
        sred[tid] = fabsf(vv[tid]) + fabsf(vv[tid + 256]);
        __syncthreads();
        for (int s = 128; s > 0; s >>= 1) {
            if (tid < s) sred[tid] += sred[tid + s];
            __syncthreads();
        }
        if (tid == 0) shiftbuf[0] = sred[0];
    }
}

// S1: gather embeddings: embP[t][k][32b]
__global__ void k_embx(const float* __restrict__ emb, const int* __restrict__ tok,
                       float* __restrict__ embP) {
    int i = blockIdx.x * 256 + threadIdx.x;
    if (i < Ss * 8192) {
        int t = i >> 13, e = i & 8191;
        int k = e >> 5, b = e & 31;
        embP[(size_t)t * 8192 + e] = emb[(size_t)tok[t * 32 + b] * Ee + k];
    }
}

// S2: Wv[b,n,d] = sum_c enc[b,n,c] * W_v[c,d]
__global__ void k_wv(const float* __restrict__ enc, const float* __restrict__ Wv_w,
                     float* __restrict__ Wv) {
    int b = blockIdx.x / 24, nt = blockIdx.x % 24, n0 = nt * 16;
    __shared__ float encL[16 * 512];
    for (int i = 0; i < 32; ++i) {
        int e = threadIdx.x + i * 256;
        int ni = e >> 9, c = e & 511;
        encL[e] = enc[((b * Nn) + (n0 + ni)) * Cc + c];
    }
    __syncthreads();
    int d0 = threadIdx.x, d1 = threadIdx.x + 256;
    float a0[16], a1[16];
#pragma unroll
    for (int i = 0; i < 16; ++i) { a0[i] = 0.f; a1[i] = 0.f; }
    for (int c = 0; c < 512; ++c) {
        float w0 = Wv_w[c * Dd + d0], w1 = Wv_w[c * Dd + d1];
#pragma unroll
        for (int i = 0; i < 16; ++i) {
            float ev = encL[i * 512 + c];
            a0[i] += ev * w0; a1[i] += ev * w1;
        }
    }
#pragma unroll
    for (int i = 0; i < 16; ++i) {
        Wv[((b * Nn) + (n0 + i)) * Dd + d0] = a0[i];
        Wv[((b * Nn) + (n0 + i)) * Dd + d1] = a1[i];
    }
}

// Persistent decode: 256 blocks x 512 threads, 4 flag-barriers per step.
// Weights stream from L2 (d_in is cacheable); activations staged in LDS.
// A: 64 blocks (16 dims x 16 batches each). C/F: (batch, colgroup) blocks.
// DE: unchanged attention with reg-hoisted Wv/enc.
__global__ __launch_bounds__(NTHR) void k_decode(
    const float* __restrict__ enc, const float* __restrict__ W_ih,
    const float* __restrict__ b_ih, const float* __restrict__ W_hh,
    const float* __restrict__ b_hh, const float* __restrict__ W_h,
    const float* __restrict__ vv, const float* __restrict__ W_c,
    const float* __restrict__ b_c, const float* __restrict__ Wv,
    const float* __restrict__ shiftbuf,
    const float* __restrict__ embP, float* __restrict__ hxP,
    float* __restrict__ hxBP, float* __restrict__ xoTP,
    float* __restrict__ den, float* __restrict__ qB, float* __restrict__ ctxB,
    float* __restrict__ obuf, float* __restrict__ alpha_e, int* bar)
{
    __shared__ float asb[1280 * 16];   // A: staged rnn_in [k][16b]   80 KiB
    __shared__ float gl[1024];         // A: gates [64col][16b]
    __shared__ float hxL[512];         // C: hx[b][:]
    __shared__ float qLs[512];         // DE: q[ab][:]
    __shared__ float xL[1024];         // F: [hx | ctx/den]
    __shared__ float cxL[256];         // A: cell state (16d x 16b)
    __shared__ float escL[64];         // DE: 48 e-values

    int* flags = bar;
    int* genv  = bar + 4096;

    const int tid = threadIdx.x, bid = blockIdx.x;
    const int lane = tid & 63;
    const int w = tid >> 6;
    // attention / C / F roles
    const int ab = bid >> 3;           // batch
    const int n0 = (bid & 7) * 48;     // DE n-slice
    const int cg = bid & 7;            // C/F col-group (== XCD id)
    // A roles (bid < 64): dims D0..D0+16, batches B0..B0+16
    const int adg = bid >> 1;
    const int D0 = adg * 16;
    const int B0 = (bid & 1) * 16;
    const int acol = tid >> 3;         // [0,64): g*16 + dloc
    const int akseg = tid & 7;
    const int ag = acol >> 4, adloc = acol & 15;
    const int awcol = ag * 512 + D0 + adloc;

    // ---- one-time ----
    if (tid < 256) cxL[tid] = 0.f;
    float v8[8];
#pragma unroll
    for (int i = 0; i < 8; ++i) v8[i] = vv[lane * 8 + i];
    float4 wva[6], wvb[6];             // t-invariant Wv fragment
#pragma unroll
    for (int r = 0; r < 6; ++r) {
        const float* wv = Wv + ((size_t)(ab * Nn + n0 + w * 6 + r)) * 512 + lane * 8;
        wva[r] = *(const float4*)wv;
        wvb[r] = *(const float4*)(wv + 4);
    }
    float encR[48];                    // t-invariant enc column slice
#pragma unroll
    for (int i = 0; i < 48; ++i)
        encR[i] = enc[((size_t)(ab * Nn + n0 + i)) * 512 + tid];
    const float SHIFT = shiftbuf[0];
    float bs0 = 0.f, bs1 = 0.f, bs2 = 0.f, bs3 = 0.f;
    if (bid < 64 && tid < 256) {
        int d = D0 + (tid >> 4);
        bs0 = b_ih[0 * 512 + d] + b_hh[0 * 512 + d];
        bs1 = b_ih[1 * 512 + d] + b_hh[1 * 512 + d];
        bs2 = b_ih[2 * 512 + d] + b_hh[2 * 512 + d];
        bs3 = b_ih[3 * 512 + d] + b_hh[3 * 512 + d];
    }
    const float bcF = b_c[cg * 64 + (tid >> 3)];
    __syncthreads();

    int ib = 0;
    for (int t = 0; t < Ss; ++t) {
        const int par = t & 1;

        // ---------- Phase A (64 blocks): gates + LSTM ----------
        if (bid < 64) {
            if (t) {
                const float* srcE = embP + (size_t)t * 8192;
                const float* srcO = xoTP + (size_t)(t - 1) * 16384;
                const float* srcH = hxP + (size_t)(t - 1) * 16384;
#pragma unroll
                for (int s = 0; s < 10; ++s) {
                    int i = s * 512 + tid;
                    const float* sp; int dst;
                    if (i < 1024) {
                        int k = i >> 2, q = i & 3;
                        sp = srcE + k * 32 + B0 + q * 4; dst = k * 16 + q * 4;
                    } else if (i < 3072) {
                        int j = i - 1024; int k = j >> 2, q = j & 3;
                        sp = srcO + k * 32 + B0 + q * 4; dst = (256 + k) * 16 + q * 4;
                    } else {
                        int j = i - 3072; int k = j >> 2, q = j & 3;
                        sp = srcH + k * 32 + B0 + q * 4; dst = (768 + k) * 16 + q * 4;
                    }
                    *(float4*)&asb[dst] = *(const float4*)sp;
                }
            }
            __syncthreads();
            float acc[16];
#pragma unroll
            for (int j = 0; j < 16; ++j) acc[j] = 0.f;
            if (t) {
                int k0 = akseg * 160;
                for (int kk = 0; kk < 160; ++kk) {
                    int k = k0 + kk;
                    const float* wr = (k < 768)
                        ? (W_ih + (size_t)k * 2048 + awcol)
                        : (W_hh + (size_t)(k - 768) * 2048 + awcol);
                    float wv_ = *wr;
                    float4 a0 = *(const float4*)&asb[k * 16];
                    float4 a1 = *(const float4*)&asb[k * 16 + 4];
                    float4 a2 = *(const float4*)&asb[k * 16 + 8];
                    float4 a3 = *(const float4*)&asb[k * 16 + 12];
                    acc[0]  += wv_ * a0.x; acc[1]  += wv_ * a0.y;
                    acc[2]  += wv_ * a0.z; acc[3]  += wv_ * a0.w;
                    acc[4]  += wv_ * a1.x; acc[5]  += wv_ * a1.y;
                    acc[6]  += wv_ * a1.z; acc[7]  += wv_ * a1.w;
                    acc[8]  += wv_ * a2.x; acc[9]  += wv_ * a2.y;
                    acc[10] += wv_ * a2.z; acc[11] += wv_ * a2.w;
                    acc[12] += wv_ * a3.x; acc[13] += wv_ * a3.y;
                    acc[14] += wv_ * a3.z; acc[15] += wv_ * a3.w;
                }
            }
#pragma unroll
            for (int j = 0; j < 16; ++j) {
                float s = acc[j];
                s += __shfl_down(s, 4, 8);
                s += __shfl_down(s, 2, 8);
                s += __shfl_down(s, 1, 8);
                acc[j] = s;
            }
            if (akseg == 0) {
#pragma unroll
                for (int j = 0; j < 16; ++j) gl[acol * 16 + j] = acc[j];
            }
            __syncthreads();
            if (tid < 256) {
                int dloc = tid >> 4, b2 = tid & 15;
                float gi = gl[(0 * 16 + dloc) * 16 + b2] + bs0;
                float gf = gl[(1 * 16 + dloc) * 16 + b2] + bs1;
                float gg = gl[(2 * 16 + dloc) * 16 + b2] + bs2;
                float go = gl[(3 * 16 + dloc) * 16 + b2] + bs3;
                float c = sigm_(gf) * cxL[tid] + sigm_(gi) * tanh_(gg);
                cxL[tid] = c;
                float h = sigm_(go) * tanh_(c);
                st_dev(&hxP[(size_t)t * 16384 + (D0 + dloc) * 32 + B0 + b2], h);
                st_dev(&hxBP[(size_t)t * 16384 + (size_t)(B0 + b2) * 512 + D0 + dloc], h);
            }
        }
        gbar(flags, genv, ib++);

        // ---------- Phase C (256 blocks): q[b][cg*64..] = hx[b] @ W_h slice ----------
        {
            if (tid < 128)
                *(float4*)&hxL[4 * tid] =
                    *(const float4*)(hxBP + (size_t)t * 16384 + ab * 512 + 4 * tid);
            else if (tid < 192)
                st_dev(&ctxB[(size_t)par * 16384 + ab * 512 + cg * 64 + (tid - 128)], 0.f);
            __syncthreads();
            int col = tid >> 3, kseg = tid & 7;
            float a = 0.f;
            int k0 = kseg * 64;
            const float* wp = W_h + (size_t)k0 * 512 + cg * 64 + col;
#pragma unroll 8
            for (int kk = 0; kk < 64; ++kk)
                a += wp[(size_t)kk * 512] * hxL[k0 + kk];
            a += __shfl_down(a, 4, 8);
            a += __shfl_down(a, 2, 8);
            a += __shfl_down(a, 1, 8);
            if (kseg == 0) st_dev(&qB[ab * 512 + cg * 64 + col], a);
        }
        gbar(flags, genv, ib++);

        // ---------- Phase DE: scores + exp(shifted) + ctx atomics ----------
        {
            if (tid < 256) {
                float2 f = ld2_dev(&qB[ab * 512 + 2 * tid]);
                qLs[2 * tid] = f.x; qLs[2 * tid + 1] = f.y;
            }
            __syncthreads();
            float q8[8];
            {
                float4 qa = *(const float4*)&qLs[lane * 8];
                float4 qb_ = *(const float4*)&qLs[lane * 8 + 4];
                q8[0] = qa.x; q8[1] = qa.y; q8[2] = qa.z; q8[3] = qa.w;
                q8[4] = qb_.x; q8[5] = qb_.y; q8[6] = qb_.z; q8[7] = qb_.w;
            }
#pragma unroll
            for (int r = 0; r < 6; ++r) {
                float s = v8[0] * tanh_(q8[0] + wva[r].x) + v8[1] * tanh_(q8[1] + wva[r].y)
                        + v8[2] * tanh_(q8[2] + wva[r].z) + v8[3] * tanh_(q8[3] + wva[r].w)
                        + v8[4] * tanh_(q8[4] + wvb[r].x) + v8[5] * tanh_(q8[5] + wvb[r].y)
                        + v8[6] * tanh_(q8[6] + wvb[r].z) + v8[7] * tanh_(q8[7] + wvb[r].w);
#pragma unroll
                for (int off = 32; off > 0; off >>= 1)
                    s += __shfl_down(s, off, 64);
                if (lane == 0) escL[w * 6 + r] = __expf(s - SHIFT);
            }
            __syncthreads();
            if (tid < 48)
                alpha_e[((size_t)ab * Ss + t) * Nn + n0 + tid] = escL[tid];
            if (tid == 0) {
                float sd = 0.f;
                for (int i = 0; i < 48; ++i) sd += escL[i];
                atomicAdd(&den[t * 32 + ab], sd);
            }
            float acc = 0.f;
#pragma unroll 8
            for (int i = 0; i < 48; ++i)
                acc += escL[i] * encR[i];
            atomicAdd(&ctxB[(size_t)par * 16384 + ab * 512 + tid], acc);
        }
        gbar(flags, genv, ib++);

        // ---------- Phase F (256 blocks): o[b][cg*64..] = tanh(x @ W_c slice + b_c) ----------
        {
            if (tid < 128)
                *(float4*)&xL[4 * tid] =
                    *(const float4*)(hxBP + (size_t)t * 16384 + ab * 512 + 4 * tid);
            else if (tid < 384) {
                int i = tid - 128;
                float dn = ld1_dev(&den[t * 32 + ab]);
                float rd = 1.0f / dn;
                float2 f = ld2_dev(&ctxB[(size_t)par * 16384 + ab * 512 + 2 * i]);
                xL[512 + 2 * i] = f.x * rd;
                xL[512 + 2 * i + 1] = f.y * rd;
            }
            __syncthreads();
            int col = tid >> 3, kseg = tid & 7;
            float a = 0.f;
            int k0 = kseg * 128;
            const float* wp = W_c + (size_t)k0 * 512 + cg * 64 + col;
#pragma unroll 8
            for (int kk = 0; kk < 128; ++kk)
                a += wp[(size_t)kk * 512] * xL[k0 + kk];
            a += __shfl_down(a, 4, 8);
            a += __shfl_down(a, 2, 8);
            a += __shfl_down(a, 1, 8);
            if (kseg == 0) {
                float o = tanh_(a + bcF);
                st_dev(&obuf[(size_t)(t + 1) * BD + ab * 512 + cg * 64 + col], o);
                st_dev(&xoTP[(size_t)t * 16384 + (cg * 64 + col) * 32 + ab], o);
            }
        }
        gbar(flags, genv, ib++);
    }
}

// Deferred logits GEMM.
__global__ void k_logits(const float* __restrict__ obuf, const float* __restrict__ W_out,
                         const float* __restrict__ b_out, float* __restrict__ out_logits) {
    int b = blockIdx.x / 24, tt = blockIdx.x % 24;
    int t0 = tt * 8;
    int tmax = min(8, Ss - t0);
    __shared__ float oL[8 * 512];
    int tid = threadIdx.x;
    for (int i = 0; i < 16; ++i) {
        int e = tid + i * 256;
        int ti = e >> 9, d = e & 511;
        oL[e] = (ti < tmax) ? obuf[(size_t)(t0 + ti + 1) * BD + b * Dd + d] : 0.f;
    }
    __syncthreads();
    int v0 = tid, v1 = tid + 256, v2 = tid + 512;
    bool h2 = (v2 < Vv);
    int v2c = h2 ? v2 : 0;
    float acc[3][8];
#pragma unroll
    for (int s = 0; s < 3; ++s)
#pragma unroll
        for (int ti = 0; ti < 8; ++ti) acc[s][ti] = 0.f;
    for (int d = 0; d < 512; ++d) {
        float w0 = W_out[d * Vv + v0];
        float w1 = W_out[d * Vv + v1];
        float w2 = W_out[d * Vv + v2c];
#pragma unroll
        for (int ti = 0; ti < 8; ++ti) {
            float o = oL[ti * 512 + d];
            acc[0][ti] += o * w0; acc[1][ti] += o * w1; acc[2][ti] += o * w2;
        }
    }
    for (int ti = 0; ti < tmax; ++ti) {
        size_t base = (size_t)b * (Ss * Vv) + (size_t)(t0 + ti) * Vv;
        out_logits[base + v0] = acc[0][ti] + b_out[v0];
        out_logits[base + v1] = acc[1][ti] + b_out[v1];
        if (h2) out_logits[base + v2] = acc[2][ti] + b_out[v2];
    }
}

// Normalize alphas: alpha /= denom[b,t]
__global__ void k_anorm(float* __restrict__ alph, const float* __restrict__ den) {
    int i = blockIdx.x * 256 + threadIdx.x;
    if (i < ALPHA_SZ) {
        int bt = i / Nn;
        int t = bt % Ss, b = bt / Ss;
        alph[i] = alph[i] / den[t * 32 + b];
    }
}

extern "C" void kernel_launch(void* const* d_in, const int* in_sizes, int n_in,
                              void* d_out, int out_size, void* d_ws, size_t ws_size,
                              hipStream_t stream) {
    const float* enc   = (const float*)d_in[0];
    const int*   tgt   = (const int*)d_in[1];
    const float* emb   = (const float*)d_in[2];
    const float* W_ih  = (const float*)d_in[3];
    const float* b_ih  = (const float*)d_in[4];
    const float* W_hh  = (const float*)d_in[5];
    const float* b_hh  = (const float*)d_in[6];
    const float* W_h   = (const float*)d_in[7];
    const float* W_v   = (const float*)d_in[8];
    const float* vv    = (const float*)d_in[9];
    const float* W_c   = (const float*)d_in[10];
    const float* b_c   = (const float*)d_in[11];
    const float* W_out = (const float*)d_in[12];
    const float* b_out = (const float*)d_in[13];

    float* wsf   = (float*)d_ws;
    int*   tok   = (int*)d_ws;
    float* shiftb= wsf + OFF_SHIFT;
    float* Wv    = wsf + OFF_WV;
    float* den   = wsf + OFF_DEN;
    float* qB    = wsf + OFF_QB;
    float* ctxB  = wsf + OFF_CTXB;
    float* embP  = wsf + OFF_EMBP;
    float* hxP   = wsf + OFF_HXP;
    float* hxBP  = wsf + OFF_HXBP;
    float* xoTP  = wsf + OFF_XOTP;
    float* obuf  = wsf + OFF_OBUF;
    int*   bar   = (int*)(wsf + OFF_BAR);

    float* out_logits = (float*)d_out;
    float* out_alphas = (float*)d_out + LOGITS_SZ;

    k_setup<<<96, 256, 0, stream>>>(tgt, vv, den, bar, tok, shiftb);
    k_embx<<<(Ss * 8192 + 255) / 256, 256, 0, stream>>>(emb, tok, embP);
    k_wv<<<768, 256, 0, stream>>>(enc, W_v, Wv);
    k_decode<<<NBLK, NTHR, 0, stream>>>(enc, W_ih, b_ih, W_hh, b_hh, W_h, vv,
                                        W_c, b_c, Wv, shiftb,
                                        embP, hxP, hxBP, xoTP, den, qB, ctxB,
                                        obuf, out_alphas, bar);
    k_logits<<<768, 256, 0, stream>>>(obuf, W_out, b_out, out_logits);
    k_anorm<<<(ALPHA_SZ + 255) / 256, 256, 0, stream>>>(out_alphas, den);
}

// Round 5
// 12447.522 us; speedup vs baseline: 1.6856x; 1.6856x over previous
//
#include <hip/hip_runtime.h>
#include <cstdint>

#define Bb 32
#define Cc 512
#define Nn 384
#define Vv 600
#define Ee 256
#define Dd 512
#define Tt 192
#define Ss 191
#define EOS_TOK 130
#define BD (Bb*Dd)          // 16384
#define NBLK 256
#define NTHR 512

// ---- ws layout (float offsets) ----
#define OFF_TOK   0                           // int tok[Ss*Bb]
#define OFF_SHIFT 8192
#define OFF_WV    8256                        // Bb*Nn*Dd = 6291456
#define OFF_DEN   6299712                     // den[t][b] (zeroed once; per-(t,b) write-once)
#define OFF_QB    6307904                     // q[b][d] 32*512 (C writes, DE reads)
#define OFF_CTXB  6324288                     // ctx[b][c] 16384 (C zeroes, DE atomics, F reads)
#define OFF_HXB   6340672                     // hxB[par][b][d] 2*16384 (A writes, A/C/F read)
#define OFF_EMBB  6373440                     // embB[t][b][k] 191*8192 (k_embx, write-once)
#define OFF_OBUF  7938112                     // obuf[t+1][b][d] 192*16384 (F st_dev; A + k_logits read)
#define OFF_BAR   11083840                    // int flags[256*16] + genv[32*16]

#define LOGITS_SZ (Bb*Ss*Vv)  // 3667200
#define ALPHA_SZ  (Bb*Ss*Nn)  // 2347008

// LDS row pads (bank skew)
#define XAP  1288   // xA row stride  (1288%32==8)
#define GAP  264    // gredA row      (264%32==8)
#define HLP  520    // hxL row        (520%32==8)
#define XFP  1036   // xF row         (1036%32==12)
#define GCP  72     // gredC row      (72%32==8)
#define QP   66     // qLsT row       (66%32==2)

__device__ __forceinline__ float sigm_(float x) {
    float e = __expf(-x);
    return __builtin_amdgcn_rcpf(1.0f + e);
}
__device__ __forceinline__ float tanh_(float x) {
    float xc = fminf(15.0f, fmaxf(-15.0f, x));
    float e = __expf(2.0f * xc);
    return (e - 1.0f) * __builtin_amdgcn_rcpf(e + 1.0f);
}

__device__ __forceinline__ void st_dev(float* p, float v) {
    __hip_atomic_store(p, v, __ATOMIC_RELAXED, __HIP_MEMORY_SCOPE_AGENT);
}
__device__ __forceinline__ float ld1_dev(const float* p) {
    return __hip_atomic_load(p, __ATOMIC_RELAXED, __HIP_MEMORY_SCOPE_AGENT);
}
__device__ __forceinline__ float2 ld2_dev(const float* p) {
    unsigned long long u = __hip_atomic_load((const unsigned long long*)p,
                                             __ATOMIC_RELAXED,
                                             __HIP_MEMORY_SCOPE_AGENT);
    float2 f;
    f.x = __uint_as_float((unsigned int)u);
    f.y = __uint_as_float((unsigned int)(u >> 32));
    return f;
}

// Flag-array device barrier (byte-identical to round 3's proven version).
__device__ __forceinline__ void gbar(int* flags, int* genv, int ibar) {
    __syncthreads();   // drains vmcnt: all sc1 data stores ack'd
    const int target = ibar + 1;
    if (threadIdx.x == 0)
        __hip_atomic_store(&flags[blockIdx.x * 16], target, __ATOMIC_RELAXED,
                           __HIP_MEMORY_SCOPE_AGENT);
    if (blockIdx.x == 0) {
        if (threadIdx.x < 64) {
            int l = threadIdx.x * 4;
            for (;;) {
                int f0 = __hip_atomic_load(&flags[(l + 0) * 16], __ATOMIC_RELAXED,
                                           __HIP_MEMORY_SCOPE_AGENT);
                int f1 = __hip_atomic_load(&flags[(l + 1) * 16], __ATOMIC_RELAXED,
                                           __HIP_MEMORY_SCOPE_AGENT);
                int f2 = __hip_atomic_load(&flags[(l + 2) * 16], __ATOMIC_RELAXED,
                                           __HIP_MEMORY_SCOPE_AGENT);
                int f3 = __hip_atomic_load(&flags[(l + 3) * 16], __ATOMIC_RELAXED,
                                           __HIP_MEMORY_SCOPE_AGENT);
                if (__all(f0 >= target && f1 >= target &&
                          f2 >= target && f3 >= target)) break;
                __builtin_amdgcn_s_sleep(1);
            }
            if (threadIdx.x < 32)
                __hip_atomic_store(&genv[threadIdx.x * 16], target,
                                   __ATOMIC_RELAXED, __HIP_MEMORY_SCOPE_AGENT);
        }
    } else if (threadIdx.x == 0) {
        int* g = &genv[(blockIdx.x >> 3) * 16];
        while (__hip_atomic_load(g, __ATOMIC_RELAXED,
                                 __HIP_MEMORY_SCOPE_AGENT) < target)
            __builtin_amdgcn_s_sleep(2);
    }
    __syncthreads();
}

// S0: zero den/flags, token sequence, exp-shift = sum|v|.
__global__ void k_setup(const int* __restrict__ tgt, const float* __restrict__ vv,
                        float* denb, int* bar, int* tok, float* shiftbuf) {
    int gid = blockIdx.x * 256 + threadIdx.x;
    if (gid < 8192) denb[gid] = 0.f;
    if (gid < 4608) bar[gid] = 0;
    if (blockIdx.x == 0) {
        __shared__ int is64;
        if (threadIdx.x == 0) {
            int a = 1;
            for (int k = 0; k < 32; ++k) if (tgt[2 * k + 1] != 0) a = 0;
            is64 = a;
        }
        __syncthreads();
        int b = threadIdx.x;
        if (b < Bb) {
            int fin = 0;
            tok[0 * Bb + b] = 0;
            for (int s = 1; s < Ss; ++s) {
                int li = b * Tt + s;
                int nt = is64 ? tgt[2 * li] : tgt[li];
                if (nt == EOS_TOK) fin = 1;
                tok[s * Bb + b] = fin ? 0 : nt;
            }
        }
    }
    if (blockIdx.x == 1) {
        __shared__ float sred[256];
        int tid = threadIdx.x;
        sred[tid] = fabsf(vv[tid]) + fabsf(vv[tid + 256]);
        __syncthreads();
        for (int s = 128; s > 0; s >>= 1) {
            if (tid < s) sred[tid] += sred[tid + s];
            __syncthreads();
        }
        if (tid == 0) shiftbuf[0] = sred[0];
    }
}

// S1: gather embeddings: embB[t][b][k]  (batch-major rows)
__global__ void k_embx(const float* __restrict__ emb, const int* __restrict__ tok,
                       float* __restrict__ embB) {
    int i = blockIdx.x * 256 + threadIdx.x;
    if (i < Ss * 8192) {
        int t = i >> 13, e = i & 8191;
        int b = e >> 8, k = e & 255;
        embB[(size_t)t * 8192 + e] = emb[(size_t)tok[t * 32 + b] * Ee + k];
    }
}

// S2: Wv[b,n,d] = sum_c enc[b,n,c] * W_v[c,d]
__global__ void k_wv(const float* __restrict__ enc, const float* __restrict__ Wv_w,
                     float* __restrict__ Wv) {
    int b = blockIdx.x / 24, nt = blockIdx.x % 24, n0 = nt * 16;
    __shared__ float encL[16 * 512];
    for (int i = 0; i < 32; ++i) {
        int e = threadIdx.x + i * 256;
        int ni = e >> 9, c = e & 511;
        encL[e] = enc[((b * Nn) + (n0 + ni)) * Cc + c];
    }
    __syncthreads();
    int d0 = threadIdx.x, d1 = threadIdx.x + 256;
    float a0[16], a1[16];
#pragma unroll
    for (int i = 0; i < 16; ++i) { a0[i] = 0.f; a1[i] = 0.f; }
    for (int c = 0; c < 512; ++c) {
        float w0 = Wv_w[c * Dd + d0], w1 = Wv_w[c * Dd + d1];
#pragma unroll
        for (int i = 0; i < 16; ++i) {
            float ev = encL[i * 512 + c];
            a0[i] += ev * w0; a1[i] += ev * w1;
        }
    }
#pragma unroll
    for (int i = 0; i < 16; ++i) {
        Wv[((b * Nn) + (n0 + i)) * Dd + d0] = a0[i];
        Wv[((b * Nn) + (n0 + i)) * Dd + d1] = a1[i];
    }
}

// Persistent decode: 256 blocks x 512 threads, 4 gbar/step.
// Block = (dgrp = bid&15 [32 dims], bgrp = bid>>4 [2 batches]).
// dgrp = bid&15 keeps all blocks sharing a weight slice on one XCD (bid%8),
// so the streamed W_ih/W_hh/W_h/W_c slices stay L2-resident (~1.5 MB/XCD).
// Per-block activation read: 10 KB/step (vs 160 KB in the broadcast design).
// DE keeps the (ab = bid>>3, n-slice = bid&7) attention mapping with
// t-invariant Wv+enc fragments in VGPRs.
__global__ __launch_bounds__(NTHR) void k_decode(
    const float* __restrict__ enc, const float* __restrict__ W_ih,
    const float* __restrict__ b_ih, const float* __restrict__ W_hh,
    const float* __restrict__ b_hh, const float* __restrict__ W_h,
    const float* __restrict__ vv, const float* __restrict__ W_c,
    const float* __restrict__ b_c, const float* __restrict__ Wv,
    const float* __restrict__ shiftbuf,
    const float* __restrict__ embB, float* __restrict__ hxB,
    float* __restrict__ den, float* __restrict__ qB, float* __restrict__ ctxB,
    float* __restrict__ obuf, float* __restrict__ alpha_e, int* bar)
{
    __shared__ float xA[2 * XAP];      // A: [b][k] activations (skewed rows)
    __shared__ float gredA[8 * GAP];   // A: partials [kh][cell]
    __shared__ float gsum[256];        // A: reduced gates
    __shared__ float cxL[64];          // A: cell state (32d x 2b)
    __shared__ float hxL[2 * HLP];     // C: hx rows
    __shared__ float xF[2 * XFP];      // F: [hx|ctx] rows
    __shared__ float gredC[8 * GCP];   // C/F: partials
    __shared__ float qLsT[8 * QP];     // DE: q transposed [j][lane]
    __shared__ float escL[64];         // DE: 48 e-values

    int* flags = bar;
    int* genv  = bar + 4096;

    const int tid = threadIdx.x, bid = blockIdx.x;
    const int lane = tid & 63;
    const int w = tid >> 6;
    // GEMV roles
    const int dgrp = bid & 15;         // 32 dims: [dgrp*32, +32)
    const int B0   = (bid >> 4) * 2;   // 2 batches: B0, B0+1
    const int kh   = tid >> 6;         // k-chunk (== wave)
    const int bth  = tid & 1;          // batch within pair
    const int colq = (tid >> 1) & 31;  // A: 4-col group; C/F: col
    // DE roles
    const int ab = bid >> 3;
    const int n0 = (bid & 7) * 48;

    // ---- one-time ----
    if (tid < 64) cxL[tid] = 0.f;
    float v8[8];
#pragma unroll
    for (int i = 0; i < 8; ++i) v8[i] = vv[lane * 8 + i];
    float4 wva[6], wvb[6];
#pragma unroll
    for (int r = 0; r < 6; ++r) {
        const float* wv = Wv + ((size_t)(ab * Nn + n0 + w * 6 + r)) * 512 + lane * 8;
        wva[r] = *(const float4*)wv;
        wvb[r] = *(const float4*)(wv + 4);
    }
    float encR[48];
#pragma unroll
    for (int i = 0; i < 48; ++i)
        encR[i] = enc[((size_t)(ab * Nn + n0 + i)) * 512 + tid];
    const float SHIFT = shiftbuf[0];
    // A biases (tid<64: tid = dloc*2+b)
    float bsA0 = 0.f, bsA1 = 0.f, bsA2 = 0.f, bsA3 = 0.f, bcF = 0.f;
    if (tid < 64) {
        int d = dgrp * 32 + (tid >> 1);
        bsA0 = b_ih[0 * 512 + d] + b_hh[0 * 512 + d];
        bsA1 = b_ih[1 * 512 + d] + b_hh[1 * 512 + d];
        bsA2 = b_ih[2 * 512 + d] + b_hh[2 * 512 + d];
        bsA3 = b_ih[3 * 512 + d] + b_hh[3 * 512 + d];
        bcF  = b_c[d];
    }
    __syncthreads();

    int ib = 0;
    for (int t = 0; t < Ss; ++t) {
        const int parW = t & 1;          // hxB write parity (read prev = parW^1... see below)
        const int parR = 1 - parW;       // hx(t-1) lives in hxB[(t-1)&1] = parR

        // ---------- Phase A: gates (1280-K GEMV, 128 cols x 2 b) + LSTM ----------
        {
            if (t) {
                if (tid < 128) {
                    int b = tid >> 6, k4 = (tid & 63) * 4;
                    *(float4*)&xA[b * XAP + k4] =
                        *(const float4*)(embB + (size_t)t * 8192 + (B0 + b) * 256 + k4);
                }
                int b = tid >> 8, pos = tid & 255;
                float2 f = ld2_dev(obuf + (size_t)t * BD + (B0 + b) * 512 + 2 * pos);
                xA[b * XAP + 256 + 2 * pos]     = f.x;
                xA[b * XAP + 256 + 2 * pos + 1] = f.y;
                float2 h = ld2_dev(hxB + parR * 16384 + (B0 + b) * 512 + 2 * pos);
                xA[b * XAP + 768 + 2 * pos]     = h.x;
                xA[b * XAP + 768 + 2 * pos + 1] = h.y;
            }
            __syncthreads();
            const int g = colq >> 3, dloc0 = (colq & 7) * 4;
            const int gcol = g * 512 + dgrp * 32 + dloc0;
            float a0 = 0.f, a1 = 0.f, a2 = 0.f, a3 = 0.f;
            if (t) {
                const float* xrow = &xA[bth * XAP];
                int kbeg = kh * 160, kend = kbeg + 160;
                int e1 = kend < 768 ? kend : 768;
                const float* wp = W_ih + (size_t)kbeg * 2048 + gcol;
#pragma unroll 8
                for (int k = kbeg; k < e1; ++k, wp += 2048) {
                    float4 w4 = *(const float4*)wp;
                    float xv = xrow[k];
                    a0 += w4.x * xv; a1 += w4.y * xv;
                    a2 += w4.z * xv; a3 += w4.w * xv;
                }
                int s2 = kbeg > 768 ? kbeg : 768;
                const float* wp2 = W_hh + (size_t)(s2 - 768) * 2048 + gcol;
#pragma unroll 8
                for (int k = s2; k < kend; ++k, wp2 += 2048) {
                    float4 w4 = *(const float4*)wp2;
                    float xv = xrow[k];
                    a0 += w4.x * xv; a1 += w4.y * xv;
                    a2 += w4.z * xv; a3 += w4.w * xv;
                }
            }
            // partials: cell = (colq*4+j)*2 + b = 8*colq + 2j + b
            {
                float* gr = &gredA[kh * GAP + 8 * colq + bth];
                gr[0] = a0; gr[2] = a1; gr[4] = a2; gr[6] = a3;
            }
            __syncthreads();
            if (tid < 256) {
                float s = 0.f;
#pragma unroll
                for (int k2 = 0; k2 < 8; ++k2) s += gredA[k2 * GAP + tid];
                gsum[tid] = s;
            }
            __syncthreads();
            if (tid < 64) {
                float gi = gsum[0 * 64 + tid] + bsA0;
                float gf = gsum[1 * 64 + tid] + bsA1;
                float gg = gsum[2 * 64 + tid] + bsA2;
                float go = gsum[3 * 64 + tid] + bsA3;
                float c = sigm_(gf) * cxL[tid] + sigm_(gi) * tanh_(gg);
                cxL[tid] = c;
                float h = sigm_(go) * tanh_(c);
                st_dev(&hxB[parW * 16384 + (B0 + (tid & 1)) * 512 + dgrp * 32 + (tid >> 1)], h);
            }
        }
        gbar(flags, genv, ib++);

        // ---------- Phase C: q cols (512-K GEMV, 32 cols x 2 b) + zero ctx slice ----------
        {
            {
                int b = tid >> 8, pos = tid & 255;
                float2 h = ld2_dev(hxB + parW * 16384 + (B0 + b) * 512 + 2 * pos);
                hxL[b * HLP + 2 * pos]     = h.x;
                hxL[b * HLP + 2 * pos + 1] = h.y;
            }
            if (tid >= 448) st_dev(&ctxB[bid * 64 + (tid - 448)], 0.f);
            __syncthreads();
            float a = 0.f;
            int kbeg = kh * 64;
            const float* wp = W_h + (size_t)kbeg * 512 + dgrp * 32 + colq;
            const float* xr = &hxL[bth * HLP + kbeg];
#pragma unroll 8
            for (int kk = 0; kk < 64; ++kk)
                a += wp[(size_t)kk * 512] * xr[kk];
            gredC[kh * GCP + colq * 2 + bth] = a;
            __syncthreads();
            if (tid < 64) {
                float s = 0.f;
#pragma unroll
                for (int k2 = 0; k2 < 8; ++k2) s += gredC[k2 * GCP + tid];
                st_dev(&qB[(B0 + (tid & 1)) * 512 + dgrp * 32 + (tid >> 1)], s);
            }
        }
        gbar(flags, genv, ib++);

        // ---------- Phase DE: scores + exp(shifted) + ctx atomics ----------
        {
            if (tid < 256) {
                float2 f = ld2_dev(&qB[ab * 512 + 2 * tid]);
                int d0 = 2 * tid;
                qLsT[(d0 & 7) * QP + (d0 >> 3)]       = f.x;
                qLsT[((d0 + 1) & 7) * QP + (d0 >> 3)] = f.y;
            }
            __syncthreads();
            float q8[8];
#pragma unroll
            for (int j = 0; j < 8; ++j) q8[j] = qLsT[j * QP + lane];
#pragma unroll
            for (int r = 0; r < 6; ++r) {
                float s = v8[0] * tanh_(q8[0] + wva[r].x) + v8[1] * tanh_(q8[1] + wva[r].y)
                        + v8[2] * tanh_(q8[2] + wva[r].z) + v8[3] * tanh_(q8[3] + wva[r].w)
                        + v8[4] * tanh_(q8[4] + wvb[r].x) + v8[5] * tanh_(q8[5] + wvb[r].y)
                        + v8[6] * tanh_(q8[6] + wvb[r].z) + v8[7] * tanh_(q8[7] + wvb[r].w);
#pragma unroll
                for (int off = 32; off > 0; off >>= 1)
                    s += __shfl_down(s, off, 64);
                if (lane == 0) escL[w * 6 + r] = __expf(s - SHIFT);
            }
            __syncthreads();
            if (tid < 48)
                alpha_e[((size_t)ab * Ss + t) * Nn + n0 + tid] = escL[tid];
            if (tid == 0) {
                float sd = 0.f;
                for (int i = 0; i < 48; ++i) sd += escL[i];
                atomicAdd(&den[t * 32 + ab], sd);
            }
            float acc = 0.f;
#pragma unroll 8
            for (int i = 0; i < 48; ++i)
                acc += escL[i] * encR[i];
            atomicAdd(&ctxB[ab * 512 + tid], acc);
        }
        gbar(flags, genv, ib++);

        // ---------- Phase F: o cols (1024-K GEMV, 32 cols x 2 b) ----------
        {
            {
                int b = tid >> 8, pos = tid & 255;
                float2 h = ld2_dev(hxB + parW * 16384 + (B0 + b) * 512 + 2 * pos);
                xF[b * XFP + 2 * pos]     = h.x;
                xF[b * XFP + 2 * pos + 1] = h.y;
                float rdn = 1.0f / ld1_dev(den + t * 32 + B0 + b);
                float2 cv = ld2_dev(ctxB + (B0 + b) * 512 + 2 * pos);
                xF[b * XFP + 512 + 2 * pos]     = cv.x * rdn;
                xF[b * XFP + 512 + 2 * pos + 1] = cv.y * rdn;
            }
            __syncthreads();
            float a = 0.f;
            int kbeg = kh * 128;
            const float* wp = W_c + (size_t)kbeg * 512 + dgrp * 32 + colq;
            const float* xr = &xF[bth * XFP + kbeg];
#pragma unroll 8
            for (int kk = 0; kk < 128; ++kk)
                a += wp[(size_t)kk * 512] * xr[kk];
            gredC[kh * GCP + colq * 2 + bth] = a;
            __syncthreads();
            if (tid < 64) {
                float s = bcF;
#pragma unroll
                for (int k2 = 0; k2 < 8; ++k2) s += gredC[k2 * GCP + tid];
                float o = tanh_(s);
                st_dev(&obuf[(size_t)(t + 1) * BD + (B0 + (tid & 1)) * 512
                             + dgrp * 32 + (tid >> 1)], o);
            }
        }
        gbar(flags, genv, ib++);
    }
}

// Deferred logits GEMM.
__global__ void k_logits(const float* __restrict__ obuf, const float* __restrict__ W_out,
                         const float* __restrict__ b_out, float* __restrict__ out_logits) {
    int b = blockIdx.x / 24, tt = blockIdx.x % 24;
    int t0 = tt * 8;
    int tmax = min(8, Ss - t0);
    __shared__ float oL[8 * 512];
    int tid = threadIdx.x;
    for (int i = 0; i < 16; ++i) {
        int e = tid + i * 256;
        int ti = e >> 9, d = e & 511;
        oL[e] = (ti < tmax) ? obuf[(size_t)(t0 + ti + 1) * BD + b * Dd + d] : 0.f;
    }
    __syncthreads();
    int v0 = tid, v1 = tid + 256, v2 = tid + 512;
    bool h2 = (v2 < Vv);
    int v2c = h2 ? v2 : 0;
    float acc[3][8];
#pragma unroll
    for (int s = 0; s < 3; ++s)
#pragma unroll
        for (int ti = 0; ti < 8; ++ti) acc[s][ti] = 0.f;
    for (int d = 0; d < 512; ++d) {
        float w0 = W_out[d * Vv + v0];
        float w1 = W_out[d * Vv + v1];
        float w2 = W_out[d * Vv + v2c];
#pragma unroll
        for (int ti = 0; ti < 8; ++ti) {
            float o = oL[ti * 512 + d];
            acc[0][ti] += o * w0; acc[1][ti] += o * w1; acc[2][ti] += o * w2;
        }
    }
    for (int ti = 0; ti < tmax; ++ti) {
        size_t base = (size_t)b * (Ss * Vv) + (size_t)(t0 + ti) * Vv;
        out_logits[base + v0] = acc[0][ti] + b_out[v0];
        out_logits[base + v1] = acc[1][ti] + b_out[v1];
        if (h2) out_logits[base + v2] = acc[2][ti] + b_out[v2];
    }
}

// Normalize alphas: alpha /= denom[b,t]
__global__ void k_anorm(float* __restrict__ alph, const float* __restrict__ den) {
    int i = blockIdx.x * 256 + threadIdx.x;
    if (i < ALPHA_SZ) {
        int bt = i / Nn;
        int t = bt % Ss, b = bt / Ss;
        alph[i] = alph[i] / den[t * 32 + b];
    }
}

extern "C" void kernel_launch(void* const* d_in, const int* in_sizes, int n_in,
                              void* d_out, int out_size, void* d_ws, size_t ws_size,
                              hipStream_t stream) {
    const float* enc   = (const float*)d_in[0];
    const int*   tgt   = (const int*)d_in[1];
    const float* emb   = (const float*)d_in[2];
    const float* W_ih  = (const float*)d_in[3];
    const float* b_ih  = (const float*)d_in[4];
    const float* W_hh  = (const float*)d_in[5];
    const float* b_hh  = (const float*)d_in[6];
    const float* W_h   = (const float*)d_in[7];
    const float* W_v   = (const float*)d_in[8];
    const float* vv    = (const float*)d_in[9];
    const float* W_c   = (const float*)d_in[10];
    const float* b_c   = (const float*)d_in[11];
    const float* W_out = (const float*)d_in[12];
    const float* b_out = (const float*)d_in[13];

    float* wsf   = (float*)d_ws;
    int*   tok   = (int*)d_ws;
    float* shiftb= wsf + OFF_SHIFT;
    float* Wv    = wsf + OFF_WV;
    float* den   = wsf + OFF_DEN;
    float* qB    = wsf + OFF_QB;
    float* ctxB  = wsf + OFF_CTXB;
    float* hxB   = wsf + OFF_HXB;
    float* embB  = wsf + OFF_EMBB;
    float* obuf  = wsf + OFF_OBUF;
    int*   bar   = (int*)(wsf + OFF_BAR);

    float* out_logits = (float*)d_out;
    float* out_alphas = (float*)d_out + LOGITS_SZ;

    k_setup<<<96, 256, 0, stream>>>(tgt, vv, den, bar, tok, shiftb);
    k_embx<<<(Ss * 8192 + 255) / 256, 256, 0, stream>>>(emb, tok, embB);
    k_wv<<<768, 256, 0, stream>>>(enc, W_v, Wv);
    k_decode<<<NBLK, NTHR, 0, stream>>>(enc, W_ih, b_ih, W_hh, b_hh, W_h, vv,
                                        W_c, b_c, Wv, shiftb,
                                        embB, hxB, den, qB, ctxB,
                                        obuf, out_alphas, bar);
    k_logits<<<768, 256, 0, stream>>>(obuf, W_out, b_out, out_logits);
    k_anorm<<<(ALPHA_SZ + 255) / 256, 256, 0, stream>>>(out_alphas, den);
}